// Round 2
// baseline (502.504 us; speedup 1.0000x reference)
//
#include <hip/hip_runtime.h>
#include <hip/hip_bf16.h>
#include <stdint.h>

#define D_MODEL 512
#define NH 8
#define DH 64
#define SEQ 4096
#define NBH 16                    // B * NH
#define XN (2 * SEQ * D_MODEL)    // 4,194,304 elements of x
#define WN (D_MODEL * D_MODEL)    // 262,144 elements per weight

typedef __attribute__((ext_vector_type(8))) short bf16x8;   // 8 bf16 = 4 VGPRs
typedef __attribute__((ext_vector_type(4))) float f32x4;

__device__ __forceinline__ short f2bf(float f) {
    union { float f; uint32_t u; } v; v.f = f;
    return (short)((v.u + 0x7FFFu + ((v.u >> 16) & 1u)) >> 16);  // RNE
}

// ---------------------------------------------------------------------------
// Kernel 0: fp32 -> bf16 convert for x and the 4 weight matrices.
// ---------------------------------------------------------------------------
__global__ __launch_bounds__(256) void cvt_kernel(
    const float* __restrict__ x,  const float* __restrict__ Wq,
    const float* __restrict__ Wk, const float* __restrict__ Wv,
    const float* __restrict__ Wp,
    short* __restrict__ xb,  short* __restrict__ Wqb,
    short* __restrict__ Wkb, short* __restrict__ Wvb,
    short* __restrict__ Wpb)
{
    const size_t total4 = (size_t)(XN + 4 * WN) / 4;
    for (size_t idx = blockIdx.x * 256 + threadIdx.x; idx < total4;
         idx += (size_t)gridDim.x * 256) {
        const size_t e = idx * 4;
        const float* src; short* dst; size_t off;
        if (e < XN) { src = x; dst = xb; off = e; }
        else {
            const size_t w = (e - XN) >> 18;          // WN == 2^18
            off = (e - XN) & (WN - 1);
            src = (w == 0) ? Wq : (w == 1) ? Wk : (w == 2) ? Wv : Wp;
            dst = (w == 0) ? Wqb : (w == 1) ? Wkb : (w == 2) ? Wvb : Wpb;
        }
        const float4 v = *(const float4*)(src + off);
        short4 o;
        o.x = f2bf(v.x); o.y = f2bf(v.y); o.z = f2bf(v.z); o.w = f2bf(v.w);
        *(short4*)(dst + off) = o;
    }
}

// ---------------------------------------------------------------------------
// Kernel 1: fused QKV projection.  out[m][n] = sum_d x[m][d] * W[n][d]
// Q,K stored [B,H,S,DH]; V stored transposed [B,H,DH,S] for the PV mfma.
// ---------------------------------------------------------------------------
__global__ __launch_bounds__(256) void qkv_kernel(
    const short* __restrict__ x,
    const short* __restrict__ Wq, const short* __restrict__ Wk,
    const short* __restrict__ Wv,
    short* __restrict__ Qb, short* __restrict__ Kb, short* __restrict__ Vt)
{
    const int wave = threadIdx.x >> 6;
    const int lane = threadIdx.x & 63;
    const int ln = lane & 15, quad = lane >> 4;
    const int z = blockIdx.z;
    const short* W = (z == 0) ? Wq : (z == 1) ? Wk : Wv;
    const int m0 = blockIdx.x * 64 + wave * 16;  // row in [0, 8192)
    const int n0 = blockIdx.y * 64;              // col in [0, 512)

    const short* xp = x + (size_t)(m0 + ln) * D_MODEL + quad * 8;
    const short* wp = W + quad * 8;

    f32x4 acc[4] = {{0,0,0,0},{0,0,0,0},{0,0,0,0},{0,0,0,0}};
    for (int kc = 0; kc < D_MODEL; kc += 32) {
        bf16x8 a = *(const bf16x8*)(xp + kc);
#pragma unroll
        for (int t = 0; t < 4; ++t) {
            bf16x8 b = *(const bf16x8*)(wp + (size_t)(n0 + t * 16 + ln) * D_MODEL + kc);
            acc[t] = __builtin_amdgcn_mfma_f32_16x16x32_bf16(a, b, acc[t], 0, 0, 0);
        }
    }
    // C layout: row = quad*4 + reg, col = ln (within 16-wide n-tile t)
#pragma unroll
    for (int t = 0; t < 4; ++t) {
        const int n = n0 + t * 16 + ln;
        const int h = n >> 6, dh = n & 63;
#pragma unroll
        for (int r = 0; r < 4; ++r) {
            const int row = m0 + quad * 4 + r;     // = b*SEQ + s
            const int bb = row >> 12, s = row & (SEQ - 1);
            const short val = f2bf(acc[t][r]);
            if (z == 2) {
                Vt[(size_t)((bb * NH + h) * DH + dh) * SEQ + s] = val;
            } else if (z == 0) {
                Qb[((size_t)((bb * NH + h) * SEQ + s) << 6) + dh] = val;
            } else {
                Kb[((size_t)((bb * NH + h) * SEQ + s) << 6) + dh] = val;
            }
        }
    }
}

// ---------------------------------------------------------------------------
// Kernel 2: causal flash attention.  One wave owns a 16-row Q tile; K/V in
// 64-wide tiles.  Wave-level load balancing: wave processes tiles t and 255-t
// (uniform ~65 K-tiles per wave).  No __syncthreads: per-wave LDS region.
// ---------------------------------------------------------------------------
__global__ __launch_bounds__(256) void attn_kernel(
    const short* __restrict__ Qb, const short* __restrict__ Kb,
    const short* __restrict__ Vt, short* __restrict__ ao)
{
    __shared__ __align__(16) short pbuf[4][16][72];  // per-wave P tile, padded
    const int wave = threadIdx.x >> 6;
    const int lane = threadIdx.x & 63;
    const int ln = lane & 15, quad = lane >> 4;
    const int bh = blockIdx.y;
    const short* Qp = Qb + (size_t)bh * SEQ * DH;
    const short* Kp = Kb + (size_t)bh * SEQ * DH;
    const short* Vp = Vt + (size_t)bh * DH * SEQ;
    const int bb = bh >> 3, h = bh & 7;
    const int tA = blockIdx.x * 4 + wave;  // 0..127
    const float cs = 0.18033688011112042f; // (1/sqrt(64)) * log2(e)

#pragma unroll 1
    for (int pass = 0; pass < 2; ++pass) {
        const int t16 = pass ? (255 - tA) : tA;   // 16-row Q tile index
        const int q0 = t16 * 16;
        const int jmax = t16 >> 2;                // last (diagonal) 64-wide K tile

        bf16x8 qf0 = *(const bf16x8*)(Qp + (size_t)(q0 + ln) * DH + quad * 8);
        bf16x8 qf1 = *(const bf16x8*)(Qp + (size_t)(q0 + ln) * DH + 32 + quad * 8);

        float m_i[4], l_i[4];
        f32x4 o[4] = {{0,0,0,0},{0,0,0,0},{0,0,0,0},{0,0,0,0}};
#pragma unroll
        for (int r = 0; r < 4; ++r) { m_i[r] = -3e38f; l_i[r] = 0.f; }

        for (int j = 0; j <= jmax; ++j) {
            const int k0 = j * 64;
            // ---- scores S = Q K^T (16 x 64), C-layout ----
            f32x4 sacc[4] = {{0,0,0,0},{0,0,0,0},{0,0,0,0},{0,0,0,0}};
#pragma unroll
            for (int t = 0; t < 4; ++t) {
                const short* kr = Kp + (size_t)(k0 + t * 16 + ln) * DH + quad * 8;
                bf16x8 b0 = *(const bf16x8*)(kr);
                bf16x8 b1 = *(const bf16x8*)(kr + 32);
                sacc[t] = __builtin_amdgcn_mfma_f32_16x16x32_bf16(qf0, b0, sacc[t], 0, 0, 0);
                sacc[t] = __builtin_amdgcn_mfma_f32_16x16x32_bf16(qf1, b1, sacc[t], 0, 0, 0);
            }
            // ---- causal mask on diagonal tile ----
            if (j == jmax) {
#pragma unroll
                for (int t = 0; t < 4; ++t) {
                    const int col = k0 + t * 16 + ln;
#pragma unroll
                    for (int r = 0; r < 4; ++r) {
                        const int row = q0 + quad * 4 + r;
                        if (col > row) sacc[t][r] = -3e38f;
                    }
                }
            }
            // ---- online softmax (rows live across the 16 lanes of a quad) ----
            float mx[4];
#pragma unroll
            for (int r = 0; r < 4; ++r) {
                float v = fmaxf(fmaxf(sacc[0][r], sacc[1][r]),
                                fmaxf(sacc[2][r], sacc[3][r]));
                v = fmaxf(v, __shfl_xor(v, 1));
                v = fmaxf(v, __shfl_xor(v, 2));
                v = fmaxf(v, __shfl_xor(v, 4));
                v = fmaxf(v, __shfl_xor(v, 8));
                mx[r] = v;
            }
#pragma unroll
            for (int r = 0; r < 4; ++r) {
                const float newm = fmaxf(m_i[r], mx[r]);
                const float alpha = exp2f(cs * (m_i[r] - newm));
                m_i[r] = newm;
                float rs = 0.f;
#pragma unroll
                for (int t = 0; t < 4; ++t) {
                    const float p = exp2f(cs * (sacc[t][r] - newm));
                    sacc[t][r] = p;
                    rs += p;
                }
                rs += __shfl_xor(rs, 1);
                rs += __shfl_xor(rs, 2);
                rs += __shfl_xor(rs, 4);
                rs += __shfl_xor(rs, 8);
                l_i[r] = l_i[r] * alpha + rs;
#pragma unroll
                for (int t = 0; t < 4; ++t) o[t][r] *= alpha;
            }
            // ---- P: C-layout -> A-layout via per-wave LDS round trip ----
#pragma unroll
            for (int t = 0; t < 4; ++t)
#pragma unroll
                for (int r = 0; r < 4; ++r)
                    pbuf[wave][quad * 4 + r][t * 16 + ln] = f2bf(sacc[t][r]);
            bf16x8 pa0 = *(const bf16x8*)(&pbuf[wave][ln][quad * 8]);
            bf16x8 pa1 = *(const bf16x8*)(&pbuf[wave][ln][32 + quad * 8]);
            // ---- O += P V  (b_frags contiguous thanks to V^T layout) ----
#pragma unroll
            for (int t = 0; t < 4; ++t) {
                const short* vr = Vp + (size_t)(t * 16 + ln) * SEQ + k0 + quad * 8;
                bf16x8 v0 = *(const bf16x8*)(vr);
                bf16x8 v1 = *(const bf16x8*)(vr + 32);
                o[t] = __builtin_amdgcn_mfma_f32_16x16x32_bf16(pa0, v0, o[t], 0, 0, 0);
                o[t] = __builtin_amdgcn_mfma_f32_16x16x32_bf16(pa1, v1, o[t], 0, 0, 0);
            }
        }
        // ---- normalize + store to attn buffer [B*S, D] (cols h*64+d) ----
#pragma unroll
        for (int r = 0; r < 4; ++r) {
            const float inv = 1.0f / l_i[r];
            const int qrow = q0 + quad * 4 + r;
            short* orow = ao + (size_t)(bb * SEQ + qrow) * D_MODEL + h * DH;
#pragma unroll
            for (int t = 0; t < 4; ++t)
                orow[t * 16 + ln] = f2bf(o[t][r] * inv);
        }
    }
}

// ---------------------------------------------------------------------------
// Kernel 3: output projection + fp32 bias, fp32 output.
// ---------------------------------------------------------------------------
__global__ __launch_bounds__(256) void proj_kernel(
    const short* __restrict__ attn, const short* __restrict__ Wp,
    const float* __restrict__ bias, float* __restrict__ out)
{
    const int wave = threadIdx.x >> 6;
    const int lane = threadIdx.x & 63;
    const int ln = lane & 15, quad = lane >> 4;
    const int m0 = blockIdx.x * 64 + wave * 16;
    const int n0 = blockIdx.y * 64;

    const short* xp = attn + (size_t)(m0 + ln) * D_MODEL + quad * 8;
    const short* wp = Wp + quad * 8;

    f32x4 acc[4] = {{0,0,0,0},{0,0,0,0},{0,0,0,0},{0,0,0,0}};
    for (int kc = 0; kc < D_MODEL; kc += 32) {
        bf16x8 a = *(const bf16x8*)(xp + kc);
#pragma unroll
        for (int t = 0; t < 4; ++t) {
            bf16x8 b = *(const bf16x8*)(wp + (size_t)(n0 + t * 16 + ln) * D_MODEL + kc);
            acc[t] = __builtin_amdgcn_mfma_f32_16x16x32_bf16(a, b, acc[t], 0, 0, 0);
        }
    }
    float bv[4];
#pragma unroll
    for (int t = 0; t < 4; ++t) bv[t] = bias[n0 + t * 16 + ln];
#pragma unroll
    for (int t = 0; t < 4; ++t) {
        const int n = n0 + t * 16 + ln;
#pragma unroll
        for (int r = 0; r < 4; ++r) {
            const int row = m0 + quad * 4 + r;
            out[(size_t)row * D_MODEL + n] = acc[t][r] + bv[t];
        }
    }
}

extern "C" void kernel_launch(void* const* d_in, const int* in_sizes, int n_in,
                              void* d_out, int out_size, void* d_ws, size_t ws_size,
                              hipStream_t stream) {
    const float* x  = (const float*)d_in[0];
    const float* Wq = (const float*)d_in[1];
    const float* Wk = (const float*)d_in[2];
    const float* Wv = (const float*)d_in[3];
    const float* Wp = (const float*)d_in[4];
    const float* bp = (const float*)d_in[5];
    float* out = (float*)d_out;

    // workspace layout (bf16 shorts):
    //   Qb | Kb | Vt | ab  (4 x 4,194,304 shorts = 4 x 8 MB)
    //   xb aliases ab (xb dead before attn writes ab)
    //   Wqb | Wkb | Wvb | Wpb (4 x 262,144 shorts)
    short* Qb  = (short*)d_ws;
    short* Kb  = Qb + (size_t)NBH * SEQ * DH;
    short* Vt  = Kb + (size_t)NBH * SEQ * DH;
    short* ab  = Vt + (size_t)NBH * SEQ * DH;
    short* xb  = ab;
    short* Wqb = ab + (size_t)NBH * SEQ * DH;
    short* Wkb = Wqb + WN;
    short* Wvb = Wkb + WN;
    short* Wpb = Wvb + WN;

    cvt_kernel<<<dim3(5120), 256, 0, stream>>>(x, Wq, Wk, Wv, Wp,
                                               xb, Wqb, Wkb, Wvb, Wpb);
    qkv_kernel<<<dim3(128, 8, 3), 256, 0, stream>>>(xb, Wqb, Wkb, Wvb, Qb, Kb, Vt);
    attn_kernel<<<dim3(32, NBH), 256, 0, stream>>>(Qb, Kb, Vt, ab);
    proj_kernel<<<dim3(128, 8), 256, 0, stream>>>(ab, Wpb, bp, out);
}

// Round 3
// 454.114 us; speedup vs baseline: 1.1066x; 1.1066x over previous
//
#include <hip/hip_runtime.h>
#include <hip/hip_bf16.h>
#include <stdint.h>

#define D_MODEL 512
#define NH 8
#define DH 64
#define SEQ 4096
#define NBH 16                    // B * NH
#define XN (2 * SEQ * D_MODEL)    // 4,194,304 elements of x
#define WN (D_MODEL * D_MODEL)    // 262,144 elements per weight

typedef __attribute__((ext_vector_type(8))) short bf16x8;   // 8 bf16 = 4 VGPRs
typedef __attribute__((ext_vector_type(4))) float f32x4;

__device__ __forceinline__ short f2bf(float f) {
    union { float f; uint32_t u; } v; v.f = f;
    return (short)((v.u + 0x7FFFu + ((v.u >> 16) & 1u)) >> 16);  // RNE
}

// async global->LDS 16B copy (global_load_lds_dwordx4)
__device__ __forceinline__ void async_cp16(const short* g, short* l) {
    __builtin_amdgcn_global_load_lds(
        (const __attribute__((address_space(1))) void*)g,
        (__attribute__((address_space(3))) void*)l, 16, 0, 0);
}

// ---------------------------------------------------------------------------
// Kernel 0: fp32 -> bf16 convert for x and the 4 weight matrices.
// ---------------------------------------------------------------------------
__global__ __launch_bounds__(256) void cvt_kernel(
    const float* __restrict__ x,  const float* __restrict__ Wq,
    const float* __restrict__ Wk, const float* __restrict__ Wv,
    const float* __restrict__ Wp,
    short* __restrict__ xb,  short* __restrict__ Wqb,
    short* __restrict__ Wkb, short* __restrict__ Wvb,
    short* __restrict__ Wpb)
{
    const size_t total4 = (size_t)(XN + 4 * WN) / 4;
    for (size_t idx = blockIdx.x * 256 + threadIdx.x; idx < total4;
         idx += (size_t)gridDim.x * 256) {
        const size_t e = idx * 4;
        const float* src; short* dst; size_t off;
        if (e < XN) { src = x; dst = xb; off = e; }
        else {
            const size_t w = (e - XN) >> 18;          // WN == 2^18
            off = (e - XN) & (WN - 1);
            src = (w == 0) ? Wq : (w == 1) ? Wk : (w == 2) ? Wv : Wp;
            dst = (w == 0) ? Wqb : (w == 1) ? Wkb : (w == 2) ? Wvb : Wpb;
        }
        const float4 v = *(const float4*)(src + off);
        short4 o;
        o.x = f2bf(v.x); o.y = f2bf(v.y); o.z = f2bf(v.z); o.w = f2bf(v.w);
        *(short4*)(dst + off) = o;
    }
}

// ---------------------------------------------------------------------------
// Kernel 1: fused QKV projection.  out[m][n] = sum_d x[m][d] * W[n][d]
// Per wave: 16 m-rows x 128 n-cols.
// Q,K stored [B,H,S,DH]; V stored transposed [B,H,DH,S] for the PV mfma.
// ---------------------------------------------------------------------------
__global__ __launch_bounds__(256) void qkv_kernel(
    const short* __restrict__ x,
    const short* __restrict__ Wq, const short* __restrict__ Wk,
    const short* __restrict__ Wv,
    short* __restrict__ Qb, short* __restrict__ Kb, short* __restrict__ Vt)
{
    const int wave = threadIdx.x >> 6;
    const int lane = threadIdx.x & 63;
    const int ln = lane & 15, quad = lane >> 4;
    const int z = blockIdx.z;
    const short* W = (z == 0) ? Wq : (z == 1) ? Wk : Wv;
    const int m0 = blockIdx.x * 64 + wave * 16;  // row in [0, 8192)
    const int n0 = blockIdx.y * 128;             // col in [0, 512)

    const short* xp = x + (size_t)(m0 + ln) * D_MODEL + quad * 8;
    const short* wp = W + quad * 8;

    f32x4 acc[8] = {};
    for (int kc = 0; kc < D_MODEL; kc += 32) {
        bf16x8 a = *(const bf16x8*)(xp + kc);
#pragma unroll
        for (int t = 0; t < 8; ++t) {
            bf16x8 b = *(const bf16x8*)(wp + (size_t)(n0 + t * 16 + ln) * D_MODEL + kc);
            acc[t] = __builtin_amdgcn_mfma_f32_16x16x32_bf16(a, b, acc[t], 0, 0, 0);
        }
    }
    // C layout: row = quad*4 + reg, col = ln (within 16-wide n-tile t)
#pragma unroll
    for (int t = 0; t < 8; ++t) {
        const int n = n0 + t * 16 + ln;
        const int h = n >> 6, dh = n & 63;
#pragma unroll
        for (int r = 0; r < 4; ++r) {
            const int row = m0 + quad * 4 + r;     // = b*SEQ + s
            const int bb = row >> 12, s = row & (SEQ - 1);
            const short val = f2bf(acc[t][r]);
            if (z == 2) {
                Vt[(size_t)((bb * NH + h) * DH + dh) * SEQ + s] = val;
            } else if (z == 0) {
                Qb[((size_t)((bb * NH + h) * SEQ + s) << 6) + dh] = val;
            } else {
                Kb[((size_t)((bb * NH + h) * SEQ + s) << 6) + dh] = val;
            }
        }
    }
}

// ---------------------------------------------------------------------------
// Kernel 2: causal flash attention, block-cooperative.
// Block = 64 Q rows (4 waves x 16), all with identical jmax = g.
// K/V tiles staged in LDS via global_load_lds, double-buffered, XOR-swizzled
// 16B chunks (swizzle instead of padding: global_load_lds scatters in strict
// lane order).  One barrier per j-iteration (m97 structure).
// ---------------------------------------------------------------------------
__global__ __launch_bounds__(256) void attn_kernel(
    const short* __restrict__ Qb, const short* __restrict__ Kb,
    const short* __restrict__ Vt, short* __restrict__ ao)
{
    // kt: [key][dh] rows of 64 bf16 = 8 chunks of 16B, chunk c stored at c^(row&7)
    // vt: [dh][key] same swizzle
    __shared__ __align__(16) short kt[2][4096];
    __shared__ __align__(16) short vt[2][4096];
    __shared__ __align__(16) short pbuf[4][16][72];  // per-wave P tile, padded

    const int tid  = threadIdx.x;
    const int wave = tid >> 6;
    const int lane = tid & 63;
    const int ln = lane & 15, quad = lane >> 4;
    const int bh = blockIdx.y;
    const int g  = 63 - blockIdx.x;               // Q row-group: rows [g*64, g*64+64)
    const short* Qp = Qb + (size_t)bh * SEQ * DH;
    const short* Kp = Kb + (size_t)bh * SEQ * DH;
    const short* Vp = Vt + (size_t)bh * DH * SEQ;
    const int bb = bh >> 3, h = bh & 7;
    const float cs = 0.18033688011112042f;        // (1/sqrt(64)) * log2(e)

    const int q0 = g * 64 + wave * 16;
    const int jmax = g;

    // Q fragments: rows q0+ln, dh split into two 32-chunks
    bf16x8 qf0 = *(const bf16x8*)(Qp + (size_t)(q0 + ln) * DH + quad * 8);
    bf16x8 qf1 = *(const bf16x8*)(Qp + (size_t)(q0 + ln) * DH + 32 + quad * 8);

    // stage tile j into buffer buf (all 256 threads; 2 chunks each per array)
    auto stage = [&](int j, int buf) {
        const int k0 = j * 64;
#pragma unroll
        for (int i = 0; i < 2; ++i) {
            const int chunk = i * 256 + tid;       // 0..511
            const int r  = chunk >> 3;             // row (key for kt, dh for vt)
            const int cs_ = (chunk & 7) ^ (r & 7); // source chunk after swizzle
            async_cp16(Kp + (((size_t)(k0 + r)) << 6) + cs_ * 8,
                       &kt[buf][chunk * 8]);
            async_cp16(Vp + (size_t)r * SEQ + k0 + cs_ * 8,
                       &vt[buf][chunk * 8]);
        }
    };

    float m_i[4], l_i[4];
    f32x4 o[4] = {};
#pragma unroll
    for (int r = 0; r < 4; ++r) { m_i[r] = -3e38f; l_i[r] = 0.f; }

    stage(0, 0);

    for (int j = 0; j <= jmax; ++j) {
        const int cur = j & 1;
        __syncthreads();                  // drains buf[cur] loads (vmcnt(0))
        if (j < jmax) stage(j + 1, cur ^ 1);   // overlaps with compute below

        const int k0 = j * 64;
        // ---- scores S = Q K^T (16 x 64), C-layout; K frags from LDS ----
        f32x4 sacc[4] = {};
#pragma unroll
        for (int t = 0; t < 4; ++t) {
            const int rr = t * 16 + ln;   // key row
            const short* krow = &kt[cur][rr * 64];
            bf16x8 b0 = *(const bf16x8*)(krow + ((quad ^ (rr & 7)) * 8));
            bf16x8 b1 = *(const bf16x8*)(krow + (((quad + 4) ^ (rr & 7)) * 8));
            sacc[t] = __builtin_amdgcn_mfma_f32_16x16x32_bf16(qf0, b0, sacc[t], 0, 0, 0);
            sacc[t] = __builtin_amdgcn_mfma_f32_16x16x32_bf16(qf1, b1, sacc[t], 0, 0, 0);
        }
        // ---- causal mask on diagonal tile ----
        if (j == jmax) {
#pragma unroll
            for (int t = 0; t < 4; ++t) {
                const int col = k0 + t * 16 + ln;
#pragma unroll
                for (int r = 0; r < 4; ++r) {
                    const int row = q0 + quad * 4 + r;
                    if (col > row) sacc[t][r] = -3e38f;
                }
            }
        }
        // ---- online softmax (rows live across the 16 lanes of a quad) ----
#pragma unroll
        for (int r = 0; r < 4; ++r) {
            float v = fmaxf(fmaxf(sacc[0][r], sacc[1][r]),
                            fmaxf(sacc[2][r], sacc[3][r]));
            v = fmaxf(v, __shfl_xor(v, 1));
            v = fmaxf(v, __shfl_xor(v, 2));
            v = fmaxf(v, __shfl_xor(v, 4));
            v = fmaxf(v, __shfl_xor(v, 8));
            const float newm = fmaxf(m_i[r], v);
            const float alpha = exp2f(cs * (m_i[r] - newm));
            m_i[r] = newm;
            float rs = 0.f;
#pragma unroll
            for (int t = 0; t < 4; ++t) {
                const float p = exp2f(cs * (sacc[t][r] - newm));
                sacc[t][r] = p;
                rs += p;
            }
            rs += __shfl_xor(rs, 1);
            rs += __shfl_xor(rs, 2);
            rs += __shfl_xor(rs, 4);
            rs += __shfl_xor(rs, 8);
            l_i[r] = l_i[r] * alpha + rs;
#pragma unroll
            for (int t = 0; t < 4; ++t) o[t][r] *= alpha;
        }
        // ---- P: C-layout -> A-layout via per-wave LDS round trip ----
#pragma unroll
        for (int t = 0; t < 4; ++t)
#pragma unroll
            for (int r = 0; r < 4; ++r)
                pbuf[wave][quad * 4 + r][t * 16 + ln] = f2bf(sacc[t][r]);
        bf16x8 pa0 = *(const bf16x8*)(&pbuf[wave][ln][quad * 8]);
        bf16x8 pa1 = *(const bf16x8*)(&pbuf[wave][ln][32 + quad * 8]);
        // ---- O += P V ; V frags from LDS ----
#pragma unroll
        for (int t = 0; t < 4; ++t) {
            const int rr = t * 16 + ln;   // dh row
            const short* vrow = &vt[cur][rr * 64];
            bf16x8 v0 = *(const bf16x8*)(vrow + ((quad ^ (rr & 7)) * 8));
            bf16x8 v1 = *(const bf16x8*)(vrow + (((quad + 4) ^ (rr & 7)) * 8));
            o[t] = __builtin_amdgcn_mfma_f32_16x16x32_bf16(pa0, v0, o[t], 0, 0, 0);
            o[t] = __builtin_amdgcn_mfma_f32_16x16x32_bf16(pa1, v1, o[t], 0, 0, 0);
        }
    }
    // ---- normalize + store to attn buffer [B*S, D] (cols h*64+d) ----
#pragma unroll
    for (int r = 0; r < 4; ++r) {
        const float inv = 1.0f / l_i[r];
        const int qrow = q0 + quad * 4 + r;
        short* orow = ao + (size_t)(bb * SEQ + qrow) * D_MODEL + h * DH;
#pragma unroll
        for (int t = 0; t < 4; ++t)
            orow[t * 16 + ln] = f2bf(o[t][r] * inv);
    }
}

// ---------------------------------------------------------------------------
// Kernel 3: output projection + fp32 bias, fp32 output.  16 rows x 128 cols
// per wave.
// ---------------------------------------------------------------------------
__global__ __launch_bounds__(256) void proj_kernel(
    const short* __restrict__ attn, const short* __restrict__ Wp,
    const float* __restrict__ bias, float* __restrict__ out)
{
    const int wave = threadIdx.x >> 6;
    const int lane = threadIdx.x & 63;
    const int ln = lane & 15, quad = lane >> 4;
    const int m0 = blockIdx.x * 64 + wave * 16;
    const int n0 = blockIdx.y * 128;

    const short* xp = attn + (size_t)(m0 + ln) * D_MODEL + quad * 8;
    const short* wp = Wp + quad * 8;

    f32x4 acc[8] = {};
    for (int kc = 0; kc < D_MODEL; kc += 32) {
        bf16x8 a = *(const bf16x8*)(xp + kc);
#pragma unroll
        for (int t = 0; t < 8; ++t) {
            bf16x8 b = *(const bf16x8*)(wp + (size_t)(n0 + t * 16 + ln) * D_MODEL + kc);
            acc[t] = __builtin_amdgcn_mfma_f32_16x16x32_bf16(a, b, acc[t], 0, 0, 0);
        }
    }
#pragma unroll
    for (int t = 0; t < 8; ++t) {
        const int n = n0 + t * 16 + ln;
        const float bv = bias[n];
#pragma unroll
        for (int r = 0; r < 4; ++r) {
            const int row = m0 + quad * 4 + r;
            out[(size_t)row * D_MODEL + n] = acc[t][r] + bv;
        }
    }
}

extern "C" void kernel_launch(void* const* d_in, const int* in_sizes, int n_in,
                              void* d_out, int out_size, void* d_ws, size_t ws_size,
                              hipStream_t stream) {
    const float* x  = (const float*)d_in[0];
    const float* Wq = (const float*)d_in[1];
    const float* Wk = (const float*)d_in[2];
    const float* Wv = (const float*)d_in[3];
    const float* Wp = (const float*)d_in[4];
    const float* bp = (const float*)d_in[5];
    float* out = (float*)d_out;

    // workspace layout (bf16 shorts):
    //   Qb | Kb | Vt | ab  (4 x 4,194,304 shorts = 4 x 8 MB)
    //   xb aliases ab (xb dead before attn writes ab)
    //   Wqb | Wkb | Wvb | Wpb (4 x 262,144 shorts)
    short* Qb  = (short*)d_ws;
    short* Kb  = Qb + (size_t)NBH * SEQ * DH;
    short* Vt  = Kb + (size_t)NBH * SEQ * DH;
    short* ab  = Vt + (size_t)NBH * SEQ * DH;
    short* xb  = ab;
    short* Wqb = ab + (size_t)NBH * SEQ * DH;
    short* Wkb = Wqb + WN;
    short* Wvb = Wkb + WN;
    short* Wpb = Wvb + WN;

    cvt_kernel<<<dim3(5120), 256, 0, stream>>>(x, Wq, Wk, Wv, Wp,
                                               xb, Wqb, Wkb, Wvb, Wpb);
    qkv_kernel<<<dim3(128, 4, 3), 256, 0, stream>>>(xb, Wqb, Wkb, Wvb, Qb, Kb, Vt);
    attn_kernel<<<dim3(64, NBH), 256, 0, stream>>>(Qb, Kb, Vt, ab);
    proj_kernel<<<dim3(128, 4), 256, 0, stream>>>(ab, Wpb, bp, out);
}

// Round 4
// 331.742 us; speedup vs baseline: 1.5147x; 1.3689x over previous
//
#include <hip/hip_runtime.h>
#include <hip/hip_bf16.h>
#include <stdint.h>

#define D_MODEL 512
#define NH 8
#define DH 64
#define SEQ 4096
#define NBH 16                    // B * NH
#define XN (2 * SEQ * D_MODEL)    // 4,194,304 elements of x
#define WN (D_MODEL * D_MODEL)    // 262,144 elements per weight

typedef __attribute__((ext_vector_type(8))) short bf16x8;   // 8 bf16 = 4 VGPRs
typedef __attribute__((ext_vector_type(4))) float f32x4;

// softmax scale folded into W_q at convert time: (1/sqrt(DH)) * log2(e)
#define CSCALE 0.18033688011112042f

__device__ __forceinline__ short f2bf(float f) {
    union { float f; uint32_t u; } v; v.f = f;
    return (short)((v.u + 0x7FFFu + ((v.u >> 16) & 1u)) >> 16);  // RNE
}
// pack two f32 -> bf16x2 in one u32 (round-half-up + v_perm byte select)
__device__ __forceinline__ uint32_t pkbf(float a, float b) {
    union { float f; uint32_t u; } x, y; x.f = a; y.f = b;
    return __builtin_amdgcn_perm(y.u + 0x8000u, x.u + 0x8000u, 0x07060302u);
}

// async global->LDS 16B copy (global_load_lds_dwordx4)
__device__ __forceinline__ void async_cp16(const short* g, short* l) {
    __builtin_amdgcn_global_load_lds(
        (const __attribute__((address_space(1))) void*)g,
        (__attribute__((address_space(3))) void*)l, 16, 0, 0);
}

// ---------------------------------------------------------------------------
// Kernel 0: fp32 -> bf16 convert; W_q additionally scaled by CSCALE so
// attention scores come out pre-scaled for exp2.
// ---------------------------------------------------------------------------
__global__ __launch_bounds__(256) void cvt_kernel(
    const float* __restrict__ x,  const float* __restrict__ Wq,
    const float* __restrict__ Wk, const float* __restrict__ Wv,
    const float* __restrict__ Wp,
    short* __restrict__ xb,  short* __restrict__ Wqb,
    short* __restrict__ Wkb, short* __restrict__ Wvb,
    short* __restrict__ Wpb)
{
    const size_t total4 = (size_t)(XN + 4 * WN) / 4;
    for (size_t idx = blockIdx.x * 256 + threadIdx.x; idx < total4;
         idx += (size_t)gridDim.x * 256) {
        const size_t e = idx * 4;
        const float* src; short* dst; size_t off; float scale = 1.f;
        if (e < XN) { src = x; dst = xb; off = e; }
        else {
            const size_t w = (e - XN) >> 18;          // WN == 2^18
            off = (e - XN) & (WN - 1);
            src = (w == 0) ? Wq : (w == 1) ? Wk : (w == 2) ? Wv : Wp;
            dst = (w == 0) ? Wqb : (w == 1) ? Wkb : (w == 2) ? Wvb : Wpb;
            if (w == 0) scale = CSCALE;
        }
        const float4 v = *(const float4*)(src + off);
        short4 o;
        o.x = f2bf(v.x * scale); o.y = f2bf(v.y * scale);
        o.z = f2bf(v.z * scale); o.w = f2bf(v.w * scale);
        *(short4*)(dst + off) = o;
    }
}

// ---------------------------------------------------------------------------
// Kernel 1: fused QKV projection.  out[m][n] = sum_d x[m][d] * W[n][d]
// Q,K stored [B,H,S,DH]; V stored transposed [B,H,DH,S] (packed b64 stores).
// ---------------------------------------------------------------------------
__global__ __launch_bounds__(256) void qkv_kernel(
    const short* __restrict__ x,
    const short* __restrict__ Wq, const short* __restrict__ Wk,
    const short* __restrict__ Wv,
    short* __restrict__ Qb, short* __restrict__ Kb, short* __restrict__ Vt)
{
    const int wave = threadIdx.x >> 6;
    const int lane = threadIdx.x & 63;
    const int ln = lane & 15, quad = lane >> 4;
    const int z = blockIdx.z;
    const short* W = (z == 0) ? Wq : (z == 1) ? Wk : Wv;
    const int m0 = blockIdx.x * 64 + wave * 16;  // row in [0, 8192)
    const int n0 = blockIdx.y * 128;             // col in [0, 512)

    const short* xp = x + (size_t)(m0 + ln) * D_MODEL + quad * 8;
    const short* wp = W + quad * 8;

    f32x4 acc[8] = {};
    for (int kc = 0; kc < D_MODEL; kc += 32) {
        bf16x8 a = *(const bf16x8*)(xp + kc);
#pragma unroll
        for (int t = 0; t < 8; ++t) {
            bf16x8 b = *(const bf16x8*)(wp + (size_t)(n0 + t * 16 + ln) * D_MODEL + kc);
            acc[t] = __builtin_amdgcn_mfma_f32_16x16x32_bf16(a, b, acc[t], 0, 0, 0);
        }
    }
    // C layout: row = quad*4 + reg, col = ln (within 16-wide n-tile t)
    if (z == 2) {
        const int row0 = m0 + quad * 4;            // 4 consecutive s values
        const int bb = row0 >> 12, s = row0 & (SEQ - 1);
#pragma unroll
        for (int t = 0; t < 8; ++t) {
            const int n = n0 + t * 16 + ln;
            const int h = n >> 6, dh = n & 63;
            uint2 st;
            st.x = pkbf(acc[t][0], acc[t][1]);
            st.y = pkbf(acc[t][2], acc[t][3]);
            *(uint2*)(Vt + (size_t)((bb * NH + h) * DH + dh) * SEQ + s) = st;
        }
    } else {
        short* P = (z == 0) ? Qb : Kb;
#pragma unroll
        for (int t = 0; t < 8; ++t) {
            const int n = n0 + t * 16 + ln;
            const int h = n >> 6, dh = n & 63;
#pragma unroll
            for (int r = 0; r < 4; ++r) {
                const int row = m0 + quad * 4 + r;
                const int bb = row >> 12, s = row & (SEQ - 1);
                P[((size_t)((bb * NH + h) * SEQ + s) << 6) + dh] = f2bf(acc[t][r]);
            }
        }
    }
}

// ---------------------------------------------------------------------------
// Kernel 2: causal flash attention, S^T formulation.
// S^T = K.Q^T  (A=K from LDS, B=Q regs): lane owns one q-column (ln) ->
// softmax reduce = 15 VALU + 2 shuffles.  K rows are PERMUTED at staging
// (row 16t+4q+r holds key 32(t>>1)+8q+4(t&1)+r) so the S^T C-layout regs
// are exactly the PV B-operand fragment -> P never leaves registers.
// O computed as O^T (A=V^T from LDS, B=P): alpha & 1/l are lane-local.
// LDS = 32 KB (K/V double-buffered, XOR-swizzled 16B chunks), no pbuf.
// ---------------------------------------------------------------------------
__global__ __launch_bounds__(256) void attn_kernel(
    const short* __restrict__ Qb, const short* __restrict__ Kb,
    const short* __restrict__ Vt, short* __restrict__ ao)
{
    __shared__ __align__(16) short kt[2][4096];
    __shared__ __align__(16) short vt[2][4096];

    const int tid  = threadIdx.x;
    const int wave = tid >> 6;
    const int lane = tid & 63;
    const int ln = lane & 15, quad = lane >> 4;
    const int bh = blockIdx.y;
    // hash so co-resident blocks carry spread g values (load balance)
    const int g = (blockIdx.x + 4 * bh) & 63;     // Q row-group [g*64, g*64+64)
    const short* Qp = Qb + (size_t)bh * SEQ * DH;
    const short* Kp = Kb + (size_t)bh * SEQ * DH;
    const short* Vp = Vt + (size_t)bh * DH * SEQ;
    const int bb = bh >> 3, h = bh & 7;
    const int q0 = g * 64 + wave * 16;

    auto stage = [&](int j, int buf) {
        const int k0 = j * 64;
#pragma unroll
        for (int i = 0; i < 2; ++i) {
            const int chunk = i * 256 + tid;       // 0..511
            const int R = chunk >> 3;              // LDS row
            const int cph = chunk & 7;             // physical 16B chunk
            const int csrc = cph ^ (R & 7);        // XOR swizzle
            // K row R holds permuted key g(R)
            const int t = R >> 4, qq = (R >> 2) & 3, r = R & 3;
            const int gk = ((t >> 1) << 5) + (qq << 3) + ((t & 1) << 2) + r;
            async_cp16(Kp + (((size_t)(k0 + gk)) << 6) + csrc * 8,
                       &kt[buf][chunk * 8]);
            async_cp16(Vp + (size_t)R * SEQ + k0 + csrc * 8,
                       &vt[buf][chunk * 8]);
        }
    };

    // Q fragments (B-operand): lane holds Q[q0+ln][dh quad*8..+7]
    bf16x8 qf0 = *(const bf16x8*)(Qp + (size_t)(q0 + ln) * DH + quad * 8);
    bf16x8 qf1 = *(const bf16x8*)(Qp + (size_t)(q0 + ln) * DH + 32 + quad * 8);

    float m_i = -3e38f, l_i = 0.f;
    f32x4 o[4] = {};

    stage(0, 0);

    for (int j = 0; j <= g; ++j) {
        const int cur = j & 1;
        __syncthreads();                     // drains buf[cur] async loads
        if (j < g) stage(j + 1, cur ^ 1);    // overlaps with compute below

        // ---- S^T tiles: lane (ln,quad) reg sacc[t][r] = score for
        //      q = q0+ln, key = k0 + 32(t>>1) + 8*quad + 4(t&1) + r ----
        f32x4 sacc[4] = {};
#pragma unroll
        for (int t = 0; t < 4; ++t) {
            const int row = t * 16 + ln;
            const short* krow = &kt[cur][row * 64];
            bf16x8 a0 = *(const bf16x8*)(krow + ((quad ^ (row & 7)) * 8));
            bf16x8 a1 = *(const bf16x8*)(krow + (((quad + 4) ^ (row & 7)) * 8));
            sacc[t] = __builtin_amdgcn_mfma_f32_16x16x32_bf16(a0, qf0, sacc[t], 0, 0, 0);
            sacc[t] = __builtin_amdgcn_mfma_f32_16x16x32_bf16(a1, qf1, sacc[t], 0, 0, 0);
        }
        // ---- causal mask on diagonal tile ----
        if (j == g) {
            const int myq = q0 + ln, k0 = j * 64;
#pragma unroll
            for (int t = 0; t < 4; ++t) {
                const int kb_ = k0 + ((t >> 1) << 5) + (quad << 3) + ((t & 1) << 2);
#pragma unroll
                for (int r = 0; r < 4; ++r)
                    if (kb_ + r > myq) sacc[t][r] = -3e38f;
            }
        }
        // ---- online softmax: intra-lane reduce + 2 cross-quad shuffles ----
        float mx = sacc[0][0];
#pragma unroll
        for (int t = 0; t < 4; ++t)
#pragma unroll
            for (int r = 0; r < 4; ++r) mx = fmaxf(mx, sacc[t][r]);
        mx = fmaxf(mx, __shfl_xor(mx, 16));
        mx = fmaxf(mx, __shfl_xor(mx, 32));
        const float newm = fmaxf(m_i, mx);
        const float alpha = exp2f(m_i - newm);   // scores pre-scaled via W_q
        m_i = newm;
        float rs = 0.f;
#pragma unroll
        for (int t = 0; t < 4; ++t)
#pragma unroll
            for (int r = 0; r < 4; ++r) {
                const float p = exp2f(sacc[t][r] - newm);
                sacc[t][r] = p;
                rs += p;
            }
        rs += __shfl_xor(rs, 16);
        rs += __shfl_xor(rs, 32);
        l_i = l_i * alpha + rs;
#pragma unroll
        for (int s = 0; s < 4; ++s)
#pragma unroll
            for (int r = 0; r < 4; ++r) o[s][r] *= alpha;

        // ---- P already in B-frag order thanks to the key permutation ----
        union { uint32_t u[4]; bf16x8 v; } p1, p2;
        p1.u[0] = pkbf(sacc[0][0], sacc[0][1]);
        p1.u[1] = pkbf(sacc[0][2], sacc[0][3]);
        p1.u[2] = pkbf(sacc[1][0], sacc[1][1]);
        p1.u[3] = pkbf(sacc[1][2], sacc[1][3]);
        p2.u[0] = pkbf(sacc[2][0], sacc[2][1]);
        p2.u[1] = pkbf(sacc[2][2], sacc[2][3]);
        p2.u[2] = pkbf(sacc[3][0], sacc[3][1]);
        p2.u[3] = pkbf(sacc[3][2], sacc[3][3]);

        // ---- O^T += V^T . P^T : A=V^T from LDS, B=P regs ----
#pragma unroll
        for (int s = 0; s < 4; ++s) {
            const int row = s * 16 + ln;
            const short* vrow = &vt[cur][row * 64];
            bf16x8 a0 = *(const bf16x8*)(vrow + ((quad ^ (row & 7)) * 8));
            bf16x8 a1 = *(const bf16x8*)(vrow + (((quad + 4) ^ (row & 7)) * 8));
            o[s] = __builtin_amdgcn_mfma_f32_16x16x32_bf16(a0, p1.v, o[s], 0, 0, 0);
            o[s] = __builtin_amdgcn_mfma_f32_16x16x32_bf16(a1, p2.v, o[s], 0, 0, 0);
        }
    }
    // ---- store: lane holds O[q=q0+ln][dh = 16s + 4*quad + r] ----
    const float inv = 1.0f / l_i;
    short* orow = ao + (size_t)(bb * SEQ + q0 + ln) * D_MODEL + h * DH;
#pragma unroll
    for (int s = 0; s < 4; ++s) {
        uint2 st;
        st.x = pkbf(o[s][0] * inv, o[s][1] * inv);
        st.y = pkbf(o[s][2] * inv, o[s][3] * inv);
        *(uint2*)(orow + s * 16 + quad * 4) = st;
    }
}

// ---------------------------------------------------------------------------
// Kernel 3: output projection + fp32 bias, fp32 output.
// ---------------------------------------------------------------------------
__global__ __launch_bounds__(256) void proj_kernel(
    const short* __restrict__ attn, const short* __restrict__ Wp,
    const float* __restrict__ bias, float* __restrict__ out)
{
    const int wave = threadIdx.x >> 6;
    const int lane = threadIdx.x & 63;
    const int ln = lane & 15, quad = lane >> 4;
    const int m0 = blockIdx.x * 64 + wave * 16;
    const int n0 = blockIdx.y * 128;

    const short* xp = attn + (size_t)(m0 + ln) * D_MODEL + quad * 8;
    const short* wp = Wp + quad * 8;

    f32x4 acc[8] = {};
    for (int kc = 0; kc < D_MODEL; kc += 32) {
        bf16x8 a = *(const bf16x8*)(xp + kc);
#pragma unroll
        for (int t = 0; t < 8; ++t) {
            bf16x8 b = *(const bf16x8*)(wp + (size_t)(n0 + t * 16 + ln) * D_MODEL + kc);
            acc[t] = __builtin_amdgcn_mfma_f32_16x16x32_bf16(a, b, acc[t], 0, 0, 0);
        }
    }
#pragma unroll
    for (int t = 0; t < 8; ++t) {
        const int n = n0 + t * 16 + ln;
        const float bv = bias[n];
#pragma unroll
        for (int r = 0; r < 4; ++r) {
            const int row = m0 + quad * 4 + r;
            out[(size_t)row * D_MODEL + n] = acc[t][r] + bv;
        }
    }
}

extern "C" void kernel_launch(void* const* d_in, const int* in_sizes, int n_in,
                              void* d_out, int out_size, void* d_ws, size_t ws_size,
                              hipStream_t stream) {
    const float* x  = (const float*)d_in[0];
    const float* Wq = (const float*)d_in[1];
    const float* Wk = (const float*)d_in[2];
    const float* Wv = (const float*)d_in[3];
    const float* Wp = (const float*)d_in[4];
    const float* bp = (const float*)d_in[5];
    float* out = (float*)d_out;

    // workspace layout (bf16 shorts):
    //   Qb | Kb | Vt | ab  (4 x 4,194,304 shorts = 4 x 8 MB)
    //   xb aliases ab (xb dead before attn writes ab)
    //   Wqb | Wkb | Wvb | Wpb (4 x 262,144 shorts)
    short* Qb  = (short*)d_ws;
    short* Kb  = Qb + (size_t)NBH * SEQ * DH;
    short* Vt  = Kb + (size_t)NBH * SEQ * DH;
    short* ab  = Vt + (size_t)NBH * SEQ * DH;
    short* xb  = ab;
    short* Wqb = ab + (size_t)NBH * SEQ * DH;
    short* Wkb = Wqb + WN;
    short* Wvb = Wkb + WN;
    short* Wpb = Wvb + WN;

    cvt_kernel<<<dim3(5120), 256, 0, stream>>>(x, Wq, Wk, Wv, Wp,
                                               xb, Wqb, Wkb, Wvb, Wpb);
    qkv_kernel<<<dim3(128, 4, 3), 256, 0, stream>>>(xb, Wqb, Wkb, Wvb, Qb, Kb, Vt);
    attn_kernel<<<dim3(64, NBH), 256, 0, stream>>>(Qb, Kb, Vt, ab);
    proj_kernel<<<dim3(128, 4), 256, 0, stream>>>(ab, Wpb, bp, out);
}

// Round 5
// 215.465 us; speedup vs baseline: 2.3322x; 1.5397x over previous
//
#include <hip/hip_runtime.h>
#include <hip/hip_bf16.h>
#include <stdint.h>

#define D_MODEL 512
#define NH 8
#define DH 64
#define SEQ 4096
#define NBH 16                    // B * NH
#define XN (2 * SEQ * D_MODEL)    // 4,194,304 elements of x
#define WN (D_MODEL * D_MODEL)    // 262,144 elements per weight

typedef __attribute__((ext_vector_type(8))) short bf16x8;   // 8 bf16 = 4 VGPRs
typedef __attribute__((ext_vector_type(4))) float f32x4;

// softmax scale folded into W_q at convert time: (1/sqrt(DH)) * log2(e)
#define CSCALE 0.18033688011112042f

__device__ __forceinline__ short f2bf(float f) {
    union { float f; uint32_t u; } v; v.f = f;
    return (short)((v.u + 0x7FFFu + ((v.u >> 16) & 1u)) >> 16);  // RNE
}
// pack two f32 -> bf16x2 in one u32 (round-half-up + v_perm byte select)
__device__ __forceinline__ uint32_t pkbf(float a, float b) {
    union { float f; uint32_t u; } x, y; x.f = a; y.f = b;
    return __builtin_amdgcn_perm(y.u + 0x8000u, x.u + 0x8000u, 0x07060302u);
}

// async global->LDS 16B copy (global_load_lds_dwordx4)
__device__ __forceinline__ void async_cp16(const short* g, short* l) {
    __builtin_amdgcn_global_load_lds(
        (const __attribute__((address_space(1))) void*)g,
        (__attribute__((address_space(3))) void*)l, 16, 0, 0);
}

// ---------------------------------------------------------------------------
// Kernel 0: fp32 -> bf16 convert; W_q additionally scaled by CSCALE.
// ---------------------------------------------------------------------------
__global__ __launch_bounds__(256) void cvt_kernel(
    const float* __restrict__ x,  const float* __restrict__ Wq,
    const float* __restrict__ Wk, const float* __restrict__ Wv,
    const float* __restrict__ Wp,
    short* __restrict__ xb,  short* __restrict__ Wqb,
    short* __restrict__ Wkb, short* __restrict__ Wvb,
    short* __restrict__ Wpb)
{
    const size_t total4 = (size_t)(XN + 4 * WN) / 4;
    for (size_t idx = blockIdx.x * 256 + threadIdx.x; idx < total4;
         idx += (size_t)gridDim.x * 256) {
        const size_t e = idx * 4;
        const float* src; short* dst; size_t off; float scale = 1.f;
        if (e < XN) { src = x; dst = xb; off = e; }
        else {
            const size_t w = (e - XN) >> 18;          // WN == 2^18
            off = (e - XN) & (WN - 1);
            src = (w == 0) ? Wq : (w == 1) ? Wk : (w == 2) ? Wv : Wp;
            dst = (w == 0) ? Wqb : (w == 1) ? Wkb : (w == 2) ? Wvb : Wpb;
            if (w == 0) scale = CSCALE;
        }
        const float4 v = *(const float4*)(src + off);
        short4 o;
        o.x = f2bf(v.x * scale); o.y = f2bf(v.y * scale);
        o.z = f2bf(v.z * scale); o.w = f2bf(v.w * scale);
        *(short4*)(dst + off) = o;
    }
}

// === m97-style 128x128 GEMM core, BK=32, double-buffered LDS ==============
// LDS row = 32 shorts (64B, 4 chunks of 16B).  Conflict-free chunk swizzle:
// physical chunk p holds logical chunk p ^ ((R + (R>>2)) & 3) — within a
// 16-row fragment read each (bank-parity, chunk) cell gets exactly 2 lanes.
#define SWZ(R) (((R) + ((R) >> 2)) & 3)

// stage one 128x32 tile (A rows from src + (r0+R)*512 + kc)
__device__ __forceinline__ void stage_tile(const short* src, int r0, int kc,
                                           short* lds, int tid) {
#pragma unroll
    for (int i = 0; i < 2; ++i) {
        const int chunk = i * 256 + tid;          // 0..511
        const int R = chunk >> 2;                 // 0..127
        const int p = chunk & 3;
        const int c = p ^ SWZ(R);
        async_cp16(src + (size_t)(r0 + R) * D_MODEL + kc + c * 8,
                   lds + chunk * 8);
    }
}

// ---------------------------------------------------------------------------
// Kernel 1: fused QKV projection, LDS-staged.  Block = 128m x 128n, K=512.
// Q,K stored [B,H,S,DH]; V stored transposed [B,H,DH,S].
// ---------------------------------------------------------------------------
__global__ __launch_bounds__(256) void qkv_kernel(
    const short* __restrict__ x,
    const short* __restrict__ Wq, const short* __restrict__ Wk,
    const short* __restrict__ Wv,
    short* __restrict__ Qb, short* __restrict__ Kb, short* __restrict__ Vt)
{
    __shared__ __align__(16) short at[2][4096];   // 128 x 32
    __shared__ __align__(16) short bt[2][4096];

    const int tid  = threadIdx.x;
    const int wave = tid >> 6;
    const int lane = tid & 63;
    const int ln = lane & 15, quad = lane >> 4;
    const int z = blockIdx.z;
    const short* W = (z == 0) ? Wq : (z == 1) ? Wk : Wv;
    const int m0 = blockIdx.x * 128;
    const int n0 = blockIdx.y * 128;
    const int mh = (wave & 1) * 64, nh = (wave >> 1) * 64;

    f32x4 acc[4][4] = {};

    stage_tile(x, m0, 0, at[0], tid);
    stage_tile(W, n0, 0, bt[0], tid);

    for (int s = 0; s < 16; ++s) {
        const int cur = s & 1;
        __syncthreads();
        if (s < 15) {
            stage_tile(x, m0, (s + 1) * 32, at[cur ^ 1], tid);
            stage_tile(W, n0, (s + 1) * 32, bt[cur ^ 1], tid);
        }
        bf16x8 a[4], b[4];
#pragma unroll
        for (int i = 0; i < 4; ++i) {
            const int R = mh + i * 16 + ln;
            a[i] = *(const bf16x8*)(&at[cur][R * 32 + ((quad ^ SWZ(R)) * 8)]);
        }
#pragma unroll
        for (int j = 0; j < 4; ++j) {
            const int R = nh + j * 16 + ln;
            b[j] = *(const bf16x8*)(&bt[cur][R * 32 + ((quad ^ SWZ(R)) * 8)]);
        }
#pragma unroll
        for (int i = 0; i < 4; ++i)
#pragma unroll
            for (int j = 0; j < 4; ++j)
                acc[i][j] = __builtin_amdgcn_mfma_f32_16x16x32_bf16(
                    a[i], b[j], acc[i][j], 0, 0, 0);
    }

    // epilogue: C row = m0+mh+i*16+quad*4+r, col = n0+nh+j*16+ln
    if (z == 2) {
#pragma unroll
        for (int i = 0; i < 4; ++i) {
            const int row0 = m0 + mh + i * 16 + quad * 4;
            const int bb = row0 >> 12, sq = row0 & (SEQ - 1);
#pragma unroll
            for (int j = 0; j < 4; ++j) {
                const int n = n0 + nh + j * 16 + ln;
                const int h = n >> 6, dh = n & 63;
                uint2 st;
                st.x = pkbf(acc[i][j][0], acc[i][j][1]);
                st.y = pkbf(acc[i][j][2], acc[i][j][3]);
                *(uint2*)(Vt + (size_t)((bb * NH + h) * DH + dh) * SEQ + sq) = st;
            }
        }
    } else {
        short* P = (z == 0) ? Qb : Kb;
#pragma unroll
        for (int i = 0; i < 4; ++i)
#pragma unroll
            for (int j = 0; j < 4; ++j) {
                const int n = n0 + nh + j * 16 + ln;
                const int h = n >> 6, dh = n & 63;
#pragma unroll
                for (int r = 0; r < 4; ++r) {
                    const int row = m0 + mh + i * 16 + quad * 4 + r;
                    const int bb = row >> 12, sq = row & (SEQ - 1);
                    P[((size_t)((bb * NH + h) * SEQ + sq) << 6) + dh] =
                        f2bf(acc[i][j][r]);
                }
            }
    }
}

// ---------------------------------------------------------------------------
// Kernel 2: causal flash attention, S^T formulation (unchanged core).
// g chosen so the 4 blocks landing on one CU (linear-id stride 256) form
// {w, 63-w, w+32 mod 64, 63-(w+32 mod 64)} -> per-CU work sum == 126 iters.
// ---------------------------------------------------------------------------
__global__ __launch_bounds__(256) void attn_kernel(
    const short* __restrict__ Qb, const short* __restrict__ Kb,
    const short* __restrict__ Vt, short* __restrict__ ao)
{
    __shared__ __align__(16) short kt[2][4096];
    __shared__ __align__(16) short vt[2][4096];

    const int tid  = threadIdx.x;
    const int wave = tid >> 6;
    const int lane = tid & 63;
    const int ln = lane & 15, quad = lane >> 4;
    const int bh = blockIdx.y;
    const int w_ = (blockIdx.x + 4 * (bh & 3) + 32 * ((bh >> 3) & 1)) & 63;
    const int g  = ((bh >> 2) & 1) ? (63 - w_) : w_;
    const short* Qp = Qb + (size_t)bh * SEQ * DH;
    const short* Kp = Kb + (size_t)bh * SEQ * DH;
    const short* Vp = Vt + (size_t)bh * DH * SEQ;
    const int bb = bh >> 3, h = bh & 7;
    const int q0 = g * 64 + wave * 16;

    auto stage = [&](int j, int buf) {
        const int k0 = j * 64;
#pragma unroll
        for (int i = 0; i < 2; ++i) {
            const int chunk = i * 256 + tid;       // 0..511
            const int R = chunk >> 3;              // LDS row
            const int cph = chunk & 7;             // physical 16B chunk
            const int csrc = cph ^ (R & 7);        // XOR swizzle
            // K row R holds permuted key g(R)
            const int t = R >> 4, qq = (R >> 2) & 3, r = R & 3;
            const int gk = ((t >> 1) << 5) + (qq << 3) + ((t & 1) << 2) + r;
            async_cp16(Kp + (((size_t)(k0 + gk)) << 6) + csrc * 8,
                       &kt[buf][chunk * 8]);
            async_cp16(Vp + (size_t)R * SEQ + k0 + csrc * 8,
                       &vt[buf][chunk * 8]);
        }
    };

    bf16x8 qf0 = *(const bf16x8*)(Qp + (size_t)(q0 + ln) * DH + quad * 8);
    bf16x8 qf1 = *(const bf16x8*)(Qp + (size_t)(q0 + ln) * DH + 32 + quad * 8);

    float m_i = -3e38f, l_i = 0.f;
    f32x4 o[4] = {};

    stage(0, 0);

    for (int j = 0; j <= g; ++j) {
        const int cur = j & 1;
        __syncthreads();
        if (j < g) stage(j + 1, cur ^ 1);

        // S^T: lane (ln,quad) reg sacc[t][r] = score for q=q0+ln,
        //      key = k0 + 32(t>>1) + 8*quad + 4(t&1) + r
        f32x4 sacc[4] = {};
#pragma unroll
        for (int t = 0; t < 4; ++t) {
            const int row = t * 16 + ln;
            const short* krow = &kt[cur][row * 64];
            bf16x8 a0 = *(const bf16x8*)(krow + ((quad ^ (row & 7)) * 8));
            bf16x8 a1 = *(const bf16x8*)(krow + (((quad + 4) ^ (row & 7)) * 8));
            sacc[t] = __builtin_amdgcn_mfma_f32_16x16x32_bf16(a0, qf0, sacc[t], 0, 0, 0);
            sacc[t] = __builtin_amdgcn_mfma_f32_16x16x32_bf16(a1, qf1, sacc[t], 0, 0, 0);
        }
        if (j == g) {
            const int myq = q0 + ln, k0 = j * 64;
#pragma unroll
            for (int t = 0; t < 4; ++t) {
                const int kb_ = k0 + ((t >> 1) << 5) + (quad << 3) + ((t & 1) << 2);
#pragma unroll
                for (int r = 0; r < 4; ++r)
                    if (kb_ + r > myq) sacc[t][r] = -3e38f;
            }
        }
        // online softmax: intra-lane reduce + 2 cross-quad shuffles
        float mx = sacc[0][0];
#pragma unroll
        for (int t = 0; t < 4; ++t)
#pragma unroll
            for (int r = 0; r < 4; ++r) mx = fmaxf(mx, sacc[t][r]);
        mx = fmaxf(mx, __shfl_xor(mx, 16));
        mx = fmaxf(mx, __shfl_xor(mx, 32));
        const float newm = fmaxf(m_i, mx);
        const float alpha = exp2f(m_i - newm);
        m_i = newm;
        float rs = 0.f;
#pragma unroll
        for (int t = 0; t < 4; ++t)
#pragma unroll
            for (int r = 0; r < 4; ++r) {
                const float p = exp2f(sacc[t][r] - newm);
                sacc[t][r] = p;
                rs += p;
            }
        rs += __shfl_xor(rs, 16);
        rs += __shfl_xor(rs, 32);
        l_i = l_i * alpha + rs;
#pragma unroll
        for (int s = 0; s < 4; ++s)
#pragma unroll
            for (int r = 0; r < 4; ++r) o[s][r] *= alpha;

        union { uint32_t u[4]; bf16x8 v; } p1, p2;
        p1.u[0] = pkbf(sacc[0][0], sacc[0][1]);
        p1.u[1] = pkbf(sacc[0][2], sacc[0][3]);
        p1.u[2] = pkbf(sacc[1][0], sacc[1][1]);
        p1.u[3] = pkbf(sacc[1][2], sacc[1][3]);
        p2.u[0] = pkbf(sacc[2][0], sacc[2][1]);
        p2.u[1] = pkbf(sacc[2][2], sacc[2][3]);
        p2.u[2] = pkbf(sacc[3][0], sacc[3][1]);
        p2.u[3] = pkbf(sacc[3][2], sacc[3][3]);

#pragma unroll
        for (int s = 0; s < 4; ++s) {
            const int row = s * 16 + ln;
            const short* vrow = &vt[cur][row * 64];
            bf16x8 a0 = *(const bf16x8*)(vrow + ((quad ^ (row & 7)) * 8));
            bf16x8 a1 = *(const bf16x8*)(vrow + (((quad + 4) ^ (row & 7)) * 8));
            o[s] = __builtin_amdgcn_mfma_f32_16x16x32_bf16(a0, p1.v, o[s], 0, 0, 0);
            o[s] = __builtin_amdgcn_mfma_f32_16x16x32_bf16(a1, p2.v, o[s], 0, 0, 0);
        }
    }
    const float inv = 1.0f / l_i;
    short* orow = ao + (size_t)(bb * SEQ + q0 + ln) * D_MODEL + h * DH;
#pragma unroll
    for (int s = 0; s < 4; ++s) {
        uint2 st;
        st.x = pkbf(o[s][0] * inv, o[s][1] * inv);
        st.y = pkbf(o[s][2] * inv, o[s][3] * inv);
        *(uint2*)(orow + s * 16 + quad * 4) = st;
    }
}

// ---------------------------------------------------------------------------
// Kernel 3: output projection, LDS-staged, + fp32 bias, fp32 output.
// ---------------------------------------------------------------------------
__global__ __launch_bounds__(256) void proj_kernel(
    const short* __restrict__ attn, const short* __restrict__ Wp,
    const float* __restrict__ bias, float* __restrict__ out)
{
    __shared__ __align__(16) short at[2][4096];
    __shared__ __align__(16) short bt[2][4096];

    const int tid  = threadIdx.x;
    const int wave = tid >> 6;
    const int lane = tid & 63;
    const int ln = lane & 15, quad = lane >> 4;
    const int m0 = blockIdx.x * 128;
    const int n0 = blockIdx.y * 128;
    const int mh = (wave & 1) * 64, nh = (wave >> 1) * 64;

    f32x4 acc[4][4] = {};

    stage_tile(attn, m0, 0, at[0], tid);
    stage_tile(Wp,   n0, 0, bt[0], tid);

    for (int s = 0; s < 16; ++s) {
        const int cur = s & 1;
        __syncthreads();
        if (s < 15) {
            stage_tile(attn, m0, (s + 1) * 32, at[cur ^ 1], tid);
            stage_tile(Wp,   n0, (s + 1) * 32, bt[cur ^ 1], tid);
        }
        bf16x8 a[4], b[4];
#pragma unroll
        for (int i = 0; i < 4; ++i) {
            const int R = mh + i * 16 + ln;
            a[i] = *(const bf16x8*)(&at[cur][R * 32 + ((quad ^ SWZ(R)) * 8)]);
        }
#pragma unroll
        for (int j = 0; j < 4; ++j) {
            const int R = nh + j * 16 + ln;
            b[j] = *(const bf16x8*)(&bt[cur][R * 32 + ((quad ^ SWZ(R)) * 8)]);
        }
#pragma unroll
        for (int i = 0; i < 4; ++i)
#pragma unroll
            for (int j = 0; j < 4; ++j)
                acc[i][j] = __builtin_amdgcn_mfma_f32_16x16x32_bf16(
                    a[i], b[j], acc[i][j], 0, 0, 0);
    }
#pragma unroll
    for (int j = 0; j < 4; ++j) {
        const int n = n0 + nh + j * 16 + ln;
        const float bv = bias[n];
#pragma unroll
        for (int i = 0; i < 4; ++i)
#pragma unroll
            for (int r = 0; r < 4; ++r) {
                const int row = m0 + mh + i * 16 + quad * 4 + r;
                out[(size_t)row * D_MODEL + n] = acc[i][j][r] + bv;
            }
    }
}

extern "C" void kernel_launch(void* const* d_in, const int* in_sizes, int n_in,
                              void* d_out, int out_size, void* d_ws, size_t ws_size,
                              hipStream_t stream) {
    const float* x  = (const float*)d_in[0];
    const float* Wq = (const float*)d_in[1];
    const float* Wk = (const float*)d_in[2];
    const float* Wv = (const float*)d_in[3];
    const float* Wp = (const float*)d_in[4];
    const float* bp = (const float*)d_in[5];
    float* out = (float*)d_out;

    short* Qb  = (short*)d_ws;
    short* Kb  = Qb + (size_t)NBH * SEQ * DH;
    short* Vt  = Kb + (size_t)NBH * SEQ * DH;
    short* ab  = Vt + (size_t)NBH * SEQ * DH;
    short* xb  = ab;                              // aliased (dead before attn)
    short* Wqb = ab + (size_t)NBH * SEQ * DH;
    short* Wkb = Wqb + WN;
    short* Wvb = Wkb + WN;
    short* Wpb = Wvb + WN;

    cvt_kernel<<<dim3(5120), 256, 0, stream>>>(x, Wq, Wk, Wv, Wp,
                                               xb, Wqb, Wkb, Wvb, Wpb);
    qkv_kernel<<<dim3(64, 4, 3), 256, 0, stream>>>(xb, Wqb, Wkb, Wvb, Qb, Kb, Vt);
    attn_kernel<<<dim3(64, NBH), 256, 0, stream>>>(Qb, Kb, Vt, ab);
    proj_kernel<<<dim3(64, 4), 256, 0, stream>>>(ab, Wpb, bp, out);
}